// Round 14
// baseline (5847.030 us; speedup 1.0000x reference)
//
#include <hip/hip_runtime.h>
#include <hip/hip_bf16.h>
#include <cstdint>
#include <cstddef>

#define T_STEPS 1024
#define BATCH   128
#define INF     128   // used input features (130 minus last 2)
#define HID     512
#define NBLK    512   // bg = blk>>6 (8 groups x 16 batch), ug = blk&63 (8 units)
#define NTHR    128   // 2 waves; wave w = one 16-row tile (4 units x 4 gates), k=640
#define PK      648   // padded k stride (fp16 units) in LDS Z plane

typedef _Float16 f16x8 __attribute__((ext_vector_type(8)));
typedef float    f32x4 __attribute__((ext_vector_type(4)));

static __device__ __forceinline__ unsigned short f16b(float v) {
  _Float16 h = (_Float16)v;
  unsigned short u;
  __builtin_memcpy(&u, &h, 2);
  return u;
}
static __device__ __forceinline__ float fsigmoid(float x) {
  return 1.f / (1.f + __expf(-x));
}
static __device__ __forceinline__ float ftanh(float x) {
  return 1.f - 2.f / (__expf(2.f * x) + 1.f);
}

// ---------------- pre-pass kernels ----------------

// xp[t*8+bg][c 16][k 128] fp16
__global__ __launch_bounds__(256) void k_prep_x(const float* __restrict__ in,
                                                unsigned short* __restrict__ xp)
{
  int t = blockIdx.x >> 3, bg = blockIdx.x & 7;
  int tid = threadIdx.x;
  size_t base = (size_t)blockIdx.x * 2048;
  #pragma unroll
  for (int rep = 0; rep < 8; ++rep) {
    int idx = rep * 256 + tid;           // 0..2047
    int c = idx >> 7, k = idx & 127;
    float v = in[((size_t)(bg * 16 + c) * T_STEPS + t) * 130 + k];
    xp[base + c * 128 + k] = f16b(v);
  }
}

// W A-fragments fp16, per-lane MFMA layout.
// blk = (ug*2 + w)*20 + s   (2560 blocks x 64 threads); ug 0..63, w 0..1
// tile rows m = u_loc*4 + gate -> Grow = gate*HID + ug*8 + w*4 + u_loc
// A lane map (16x16x32): row = l&15, k = (l>>4)*8 + j
__global__ __launch_bounds__(64) void k_prep_w(const float* __restrict__ Wih,
                                               const float* __restrict__ Whh,
                                               unsigned short* __restrict__ wf)
{
  int blk = blockIdx.x;
  int s = blk % 20; int r = blk / 20;    // r = ug*2 + w
  int w = r & 1; int ug = r >> 1;
  int l = threadIdx.x;
  int m = l & 15;
  int Grow = (m & 3) * HID + ug * 8 + w * 4 + (m >> 2);
  int kb = s * 32 + (l >> 4) * 8;
  unsigned short o[8];
  #pragma unroll
  for (int j = 0; j < 8; ++j) {
    float v = (kb + j < INF) ? Wih[(size_t)Grow * INF + kb + j]
                             : Whh[(size_t)Grow * HID + (kb + j - INF)];
    o[j] = f16b(v);
  }
  unsigned short* d = wf + ((size_t)blk * 64 + l) * 8;
  #pragma unroll
  for (int j = 0; j < 8; ++j) d[j] = o[j];
}

// hp0[bg][c 16][u 512] fp16 of h0; zero 512 flags
__global__ __launch_bounds__(256) void k_prep_h(const float* __restrict__ h0,
                                                unsigned short* __restrict__ hp0,
                                                unsigned* __restrict__ flags)
{
  int idx = blockIdx.x * 256 + threadIdx.x;   // 0..65535
  int bg = idx >> 13;
  int r = idx & 8191;
  int c = r >> 9, u = r & 511;
  hp0[idx] = f16b(h0[(size_t)(bg * 16 + c) * HID + u]);
  if (idx < 512) flags[idx] = 0;
}

// ---------------- persistent MFMA LSTM: 2 independent chains per CU ----------------
// 512 blocks x 128 thr: bg = blk>>6 -> co-resident blocks (±256 apart) belong to
// DIFFERENT bg chains -> the CU wave scheduler interleaves them: one chain's
// flag-poll / h-load latency hides under the other's MFMA+update. No shared
// barriers between chains (the r9/r13 failure mode).  Sync = r6/r11 scheme.
__global__ __launch_bounds__(NTHR, 1) void k_persist(
    const unsigned short* __restrict__ xp,   // [t*8+bg][16][128] fp16
    const unsigned short* __restrict__ wf,   // A-fragments fp16
    const float* __restrict__ bih, const float* __restrict__ bhh,
    unsigned short* __restrict__ hp0,        // [8][16][512] fp16 ping
    unsigned short* __restrict__ hp1,        // pong
    const float* __restrict__ c0,            // [128][512]
    const int* __restrict__ len,
    float* __restrict__ out,                 // [128][512]
    unsigned* __restrict__ flags)            // [8][64]
{
  __shared__ short zpl[16][PK];              // [c 16][k 640 pad 648] fp16

  const int blk = blockIdx.x;
  const int bg = blk >> 6, ug = blk & 63;
  const int tid = threadIdx.x;
  const int w = tid >> 6, l = tid & 63;
  const int cB = l & 15, gch = l >> 4;

  // ---- load 20 W A-fragments into NAMED registers (once; AGPR-resident)
  const uint4* wfq = (const uint4*)wf;
  const int fb = (ug * 2 + w) * 20;
#define LDW(s_) (*reinterpret_cast<const f16x8*>(&wfq[(size_t)(fb + (s_)) * 64 + l]))
  f16x8 A0 = LDW(0),  A1 = LDW(1),  A2 = LDW(2),  A3 = LDW(3),  A4 = LDW(4);
  f16x8 A5 = LDW(5),  A6 = LDW(6),  A7 = LDW(7),  A8 = LDW(8),  A9 = LDW(9);
  f16x8 A10 = LDW(10), A11 = LDW(11), A12 = LDW(12), A13 = LDW(13), A14 = LDW(14);
  f16x8 A15 = LDW(15), A16 = LDW(16), A17 = LDW(17), A18 = LDW(18), A19 = LDW(19);
#undef LDW
  asm volatile("" : "+v"(A0), "+v"(A1), "+v"(A2), "+v"(A3), "+v"(A4),
                    "+v"(A5), "+v"(A6), "+v"(A7), "+v"(A8), "+v"(A9),
                    "+v"(A10), "+v"(A11), "+v"(A12), "+v"(A13), "+v"(A14),
                    "+v"(A15), "+v"(A16), "+v"(A17), "+v"(A18), "+v"(A19));

  // ---- per-cell state: every lane owns cell (unit hu, batch cb)
  const int cb = l & 15;
  const int uloc = l >> 4;                   // 0..3
  const int hu = ug * 8 + w * 4 + uloc;
  const int gb = bg * 16 + cb;
  float c_reg = c0[(size_t)gb * HID + hu];
  const int mylen = len[gb];
  float bsq[4];
  #pragma unroll
  for (int g = 0; g < 4; ++g) bsq[g] = bih[g * HID + hu] + bhh[g * HID + hu];

  const unsigned* fl = flags + bg * 64;
  const int hc = tid >> 3, hs = tid & 7;     // h slab: c row, sub-lane

  for (int t = 0; t < T_STEPS; ++t) {
    // ---- x load first (h-independent; latency hides under the poll)
    const uint4* xps = (const uint4*)(xp + (size_t)(t * 8 + bg) * 2048);
    uint4 xa = xps[2 * tid], xb = xps[2 * tid + 1];

    // ---- per-wave poll of the 64 peer flags (cheap detect, r6 scheme)
    if (t) {
      const unsigned* fp = fl + l;
      for (;;) {
        unsigned v = __hip_atomic_load(fp, __ATOMIC_RELAXED,
                                       __HIP_MEMORY_SCOPE_AGENT);
        if (__all((int)(v >= (unsigned)t))) break;
        __builtin_amdgcn_s_sleep(1);
      }
    }
    const unsigned long long* hq =
        (const unsigned long long*)(((t & 1) ? hp1 : hp0) + (size_t)bg * 8192);
    unsigned* hdw = (unsigned*)(((t & 1) ? hp0 : hp1) + (size_t)bg * 8192);

    // ---- bulk h load: 128B/thread (16 x u64 agent loads, one LLC RT)
    unsigned long long hch[16];
    #pragma unroll
    for (int j = 0; j < 16; ++j)
      hch[j] = __hip_atomic_load(hq + hc * 128 + j * 8 + hs,
                                 __ATOMIC_RELAXED, __HIP_MEMORY_SCOPE_AGENT);

    // ---- stage x (32B) + h (128B) into the Z plane
    {
      int c_ = tid >> 3, k0 = (tid & 7) * 16;
      *(uint4*)(&zpl[c_][k0])     = xa;
      *(uint4*)(&zpl[c_][k0 + 8]) = xb;
    }
    #pragma unroll
    for (int j = 0; j < 16; ++j)
      *(unsigned long long*)(&zpl[hc][128 + 4 * (j * 8 + hs)]) = hch[j];
    __syncthreads();   // (1) staging complete

    // ---- MFMA: 20 k-steps x 1 fp16 MFMA, full k=640
    f32x4 aE = {0, 0, 0, 0}, aO = {0, 0, 0, 0};
    const short* zr = &zpl[cB][0];
#define KS(s_, AF, ACC) \
  { f16x8 B = *(const f16x8*)(zr + (s_) * 32 + gch * 8); \
    ACC = __builtin_amdgcn_mfma_f32_16x16x32_f16(AF, B, ACC, 0, 0, 0); }
    KS(0, A0, aE)  KS(1, A1, aO)  KS(2, A2, aE)  KS(3, A3, aO)
    KS(4, A4, aE)  KS(5, A5, aO)  KS(6, A6, aE)  KS(7, A7, aO)
    KS(8, A8, aE)  KS(9, A9, aO)  KS(10, A10, aE) KS(11, A11, aO)
    KS(12, A12, aE) KS(13, A13, aO) KS(14, A14, aE) KS(15, A15, aO)
    KS(16, A16, aE) KS(17, A17, aO) KS(18, A18, aE) KS(19, A19, aO)
#undef KS

    // ---- in-lane cell update: acc[r] = gate r of (hu, cb)
    float s0 = aE[0] + aO[0] + bsq[0];
    float s1 = aE[1] + aO[1] + bsq[1];
    float s2 = aE[2] + aO[2] + bsq[2];
    float s3 = aE[3] + aO[3] + bsq[3];
    float iv = fsigmoid(s0);
    float fv = fsigmoid(s1);
    float gv = ftanh(s2);
    float ov = fsigmoid(s3);
    c_reg = fv * c_reg + iv * gv;
    float h2 = ov * ftanh(c_reg);

    // ---- pack fp16 pair across u_loc partner lanes, agent store u32
    unsigned hb = f16b(h2);
    unsigned other = __shfl_xor(hb, 16);
    if ((uloc & 1) == 0)
      __hip_atomic_store(hdw + cb * 256 + (ug * 4 + w * 2 + (uloc >> 1)),
                         hb | (other << 16),
                         __ATOMIC_RELAXED, __HIP_MEMORY_SCOPE_AGENT);
    if (t == mylen - 1) out[(size_t)gb * HID + hu] = h2;

    __syncthreads();   // (2) drain all waves' h stores before the flag
    if (tid == 0)
      __hip_atomic_store((unsigned*)(flags + bg * 64 + ug), (unsigned)(t + 1),
                         __ATOMIC_RELAXED, __HIP_MEMORY_SCOPE_AGENT);
  }
}

// ---------------- launch ----------------
extern "C" void kernel_launch(void* const* d_in, const int* in_sizes, int n_in,
                              void* d_out, int out_size, void* d_ws, size_t ws_size,
                              hipStream_t stream)
{
  const float* inputs = (const float*)d_in[0];
  const int*   len    = (const int*)  d_in[1];
  const float* h0     = (const float*)d_in[2];
  const float* c0     = (const float*)d_in[3];
  const float* Wih    = (const float*)d_in[4];
  const float* Whh    = (const float*)d_in[5];
  const float* bih    = (const float*)d_in[6];
  const float* bhh    = (const float*)d_in[7];
  float* out = (float*)d_out;

  char* p = (char*)d_ws;
  unsigned short* xp = (unsigned short*)p; p += (size_t)T_STEPS * 8 * 2048 * 2;      // 32 MB
  unsigned short* wf = (unsigned short*)p; p += (size_t)2560 * 64 * 8 * 2;           // 2.6 MB
  unsigned short* hp0 = (unsigned short*)p; p += (size_t)8 * 8192 * 2;               // 128 KB
  unsigned short* hp1 = (unsigned short*)p; p += (size_t)8 * 8192 * 2;               // 128 KB
  unsigned* flags = (unsigned*)p; p += 512 * 4;

  k_prep_x<<<T_STEPS * 8, 256, 0, stream>>>(inputs, xp);
  k_prep_w<<<2560, 64, 0, stream>>>(Wih, Whh, wf);
  k_prep_h<<<256, 256, 0, stream>>>(h0, hp0, flags);

  void* args[] = {(void*)&xp, (void*)&wf, (void*)&bih, (void*)&bhh,
                  (void*)&hp0, (void*)&hp1, (void*)&c0, (void*)&len,
                  (void*)&out, (void*)&flags};
  (void)hipLaunchCooperativeKernel((void*)k_persist, dim3(NBLK), dim3(NTHR),
                                   args, 0, stream);
}